// Round 10
// baseline (186.218 us; speedup 1.0000x reference)
//
#include <hip/hip_runtime.h>
#include <math.h>

// GGNN message-passing GRU, N=2048, SD=32, MD=16, 10 steps — MULTI-LAUNCH
// (13 kernels), deadlock-free by construction. Round-9's persistent 2-block/CU
// attempt hung (co-residency not guaranteeable); here kernel boundaries are the
// global sync. Step kernel: 512 blocks x 512 threads, NPB=4; block stages its
// 4 J-columns (32 KB, XOR-swizzled, round-7-proven pair) + weights in LDS
// (~66 KB total -> 2 blocks/CU if VGPR<=128, graceful 1/CU otherwise);
// h/msg/aj round-trip global between launches (round-2-proven); ai transposed
// [m][N], double-buffered. Phase-2 math byte-identical to round 4 (absmax 0.0).

#define GN 2048
#define GSD 32
#define GMD 16
#define GSTEPS 10
#define NPB 4            // nodes (j columns) per block
#define NBLK (GN / NPB)  // 512 blocks
#define BLK 512

// ---------------- J transpose (once) ----------------
__global__ __launch_bounds__(256)
void transpose_kernel(const float* __restrict__ J, float* __restrict__ Jt)
{
    __shared__ float tile[64][65];
    const int tx = threadIdx.x & 63;
    const int ty = threadIdx.x >> 6;
    const int bx = blockIdx.x, by = blockIdx.y;
#pragma unroll
    for (int r = ty; r < 64; r += 4)
        tile[r][tx] = J[(size_t)(by * 64 + r) * GN + bx * 64 + tx];
    __syncthreads();
#pragma unroll
    for (int r = ty; r < 64; r += 4)
        Jt[(size_t)(bx * 64 + r) * GN + by * 64 + tx] = tile[tx][r];
}

// ---------------- init: h=0, msg=0, aiT0/aj0 from h=0 ----------------
__global__ __launch_bounds__(256)
void init_kernel(const float* __restrict__ b, const float* __restrict__ Wmsg,
                 const float* __restrict__ bmsg,
                 float* __restrict__ aiT, float* __restrict__ aj,
                 float* __restrict__ h, float* __restrict__ msg)
{
    const int idx = blockIdx.x * 256 + threadIdx.x;   // grid covers GN*GSD
    if (idx < GN * GMD) {
        const int node = idx >> 4, m = idx & 15;
        const float bb = b[node];
        aiT[(size_t)m * GN + node] = fmaf(bb, Wmsg[m * 67 + 65], bmsg[m]);
        aj[idx] = bb * Wmsg[m * 67 + 66];
        msg[idx] = 0.f;
    }
    h[idx] = 0.f;
}

// ---------------- one GGNN step ----------------
__global__ __launch_bounds__(BLK, 2)
void step_kernel(const float* __restrict__ Jt,
                 const float* __restrict__ aiT_in,
                 float* __restrict__ aiT_out,
                 float* __restrict__ aj,
                 float* __restrict__ h,
                 float* __restrict__ msg,
                 const float* __restrict__ b,
                 const float* __restrict__ Wmsg,
                 const float* __restrict__ bmsg,
                 const float* __restrict__ Wih,
                 const float* __restrict__ bih,
                 const float* __restrict__ bhh)
{
    __shared__ __align__(16) float sJ[NPB][GN];    // 32 KB, XOR-swizzled rows
    __shared__ float sWih[96][49];
    __shared__ float sWhi[GMD][GSD + 1];
    __shared__ float sWhj[GMD][GSD + 1];
    __shared__ float sx[NPB][GSD + GMD];
    __shared__ float sg[NPB][3 * GSD];
    __shared__ float smsg[NPB][GMD];
    __shared__ __align__(16) float saj[NPB][GMD];
    __shared__ __align__(16) float spart[8][4][NPB][4]; // [wave][mq][jl][mi]
    __shared__ float swJ[GMD], swbi[GMD], swbj[GMD], sbm[GMD];
    __shared__ float sbih[3 * GSD], sbhh[3 * GSD];
    __shared__ float sb[NPB];

    const int t = threadIdx.x;
    const int jb = blockIdx.x * NPB;

    // ---- stage: weights + block-local state + J-slice (all before one sync) ----
    for (int idx = t; idx < 96 * 48; idx += BLK) sWih[idx / 48][idx % 48] = Wih[idx];
    if (t < GMD * GSD) {
        const int m = t >> 5, k = t & 31;
        sWhi[m][k] = Wmsg[m * 67 + k];
        sWhj[m][k] = Wmsg[m * 67 + GSD + k];
    }
    if (t < GMD) { swJ[t] = Wmsg[t * 67 + 64]; swbi[t] = Wmsg[t * 67 + 65];
                   swbj[t] = Wmsg[t * 67 + 66]; sbm[t] = bmsg[t]; }
    if (t < 96) { sbih[t] = bih[t]; sbhh[t] = bhh[t]; }
    if (t < NPB) sb[t] = b[jb + t];
    if (t < NPB * GSD) sx[t >> 5][t & 31] = h[(size_t)(jb + (t >> 5)) * GSD + (t & 31)];
    if (t < NPB * GMD) {
        smsg[t >> 4][t & 15] = msg[(size_t)(jb + (t >> 4)) * GMD + (t & 15)];
        saj[t >> 4][t & 15]  = aj[(size_t)(jb + (t >> 4)) * GMD + (t & 15)];
    }
    // J-slice: 16B-granule qi stored at byte (qi*16) ^ (((qi>>3)&7)<<4); bijective.
    for (int idx = t; idx < NPB * (GN / 4); idx += BLK) {   // 2048 float4s
        const int row = idx >> 9;
        const int qi  = idx & 511;
        const float4 v = *(const float4*)&Jt[(size_t)(jb + row) * GN + qi * 4];
        const int byte = (qi * 16) ^ (((qi >> 3) & 7) << 4);
        *(float4*)((char*)&sJ[row][0] + byte) = v;
    }
    __syncthreads();

    // ---- stream decomposition: t = isub*4 + mq ----
    const int mq   = t & 3;          // m-quad: m = mq*4 + mi
    const int isub = t >> 2;         // 0..127, owns i in [isub*16, isub*16+16)
    const int i0 = isub * 16;
    // read-side swizzle: qi_lin = isub*4 + c -> (qi_lin>>3)&7 == (isub>>1)&7
    const int swz = ((isub >> 1) & 7) << 4;
    const char* sJb = (const char*)&sJ[0][0];

    float wj[4];
#pragma unroll
    for (int mi = 0; mi < 4; ++mi) wj[mi] = swJ[mq * 4 + mi];

    // ---- phase 2: relu-sum stream; J from LDS, ai from global (L2/L3) ----
    float ajv[NPB][4];
#pragma unroll
    for (int jl = 0; jl < NPB; ++jl) {
        const float4 a = *(const float4*)&saj[jl][mq * 4];
        ajv[jl][0] = a.x; ajv[jl][1] = a.y; ajv[jl][2] = a.z; ajv[jl][3] = a.w;
    }
    const float* __restrict__ Ar[4];
#pragma unroll
    for (int mi = 0; mi < 4; ++mi) Ar[mi] = aiT_in + (size_t)(mq * 4 + mi) * GN + i0;

    float acc[NPB][4];
#pragma unroll
    for (int jl = 0; jl < NPB; ++jl)
#pragma unroll
        for (int mi = 0; mi < 4; ++mi) acc[jl][mi] = 0.f;

#pragma unroll 2
    for (int c = 0; c < 4; ++c) {
        float jv[NPB][4], av[4][4];
        const int jbyte = (i0 * 4 + c * 16) ^ swz;
#pragma unroll
        for (int jl = 0; jl < NPB; ++jl) {
            const float4 v = *(const float4*)(sJb + jl * (GN * 4) + jbyte);
            jv[jl][0] = v.x; jv[jl][1] = v.y; jv[jl][2] = v.z; jv[jl][3] = v.w;
        }
#pragma unroll
        for (int mi = 0; mi < 4; ++mi) {
            const float4 v = *(const float4*)(Ar[mi] + c * 4);
            av[mi][0] = v.x; av[mi][1] = v.y; av[mi][2] = v.z; av[mi][3] = v.w;
        }
#pragma unroll
        for (int q = 0; q < 4; ++q)
#pragma unroll
            for (int jl = 0; jl < NPB; ++jl)
#pragma unroll
                for (int mi = 0; mi < 4; ++mi)
                    acc[jl][mi] += fmaxf(fmaf(jv[jl][q], wj[mi],
                                              av[mi][q] + ajv[jl][mi]), 0.f);
    }

    // reduce over isub-within-wave (lane bits 2..5)
#pragma unroll
    for (int d = 4; d < 64; d <<= 1)
#pragma unroll
        for (int jl = 0; jl < NPB; ++jl)
#pragma unroll
            for (int mi = 0; mi < 4; ++mi)
                acc[jl][mi] += __shfl_xor(acc[jl][mi], d, 64);

    if ((t & 63) < 4) {   // lane = mq
        const int w = t >> 6;
#pragma unroll
        for (int jl = 0; jl < NPB; ++jl)
            *(float4*)&spart[w][mq][jl][0] =
                make_float4(acc[jl][0], acc[jl][1], acc[jl][2], acc[jl][3]);
    }
    __syncthreads();

    // combine 8 wave-partials, update msg (deterministic fixed order)
    if (t < NPB * GMD) {
        const int j = t >> 4, m = t & 15;
        float ssum = 0.f;
#pragma unroll
        for (int w = 0; w < 8; ++w) ssum += spart[w][m >> 2][j][m & 3];
        const float mnew = smsg[j][m] + ssum;
        msg[(size_t)(jb + j) * GMD + m] = mnew;
        sx[j][GSD + m] = mnew;
    }
    __syncthreads();

    // ---- phase 3: g = W_ih @ x + b_ih ----
    if (t < NPB * 96) {
        const int node = t / 96, r = t - node * 96;
        float a = sbih[r];
#pragma unroll
        for (int c = 0; c < GSD + GMD; ++c) a = fmaf(sWih[r][c], sx[node][c], a);
        sg[node][r] = a;
    }
    __syncthreads();

    // GRU gates -> h_new
    if (t < NPB * GSD) {
        const int node = t >> 5, k = t & 31;
        const float gr = sg[node][k]           + sbhh[k];
        const float gz = sg[node][GSD + k]     + sbhh[GSD + k];
        const float gn = sg[node][2 * GSD + k];
        const float r_ = 1.f / (1.f + expf(-gr));
        const float z_ = 1.f / (1.f + expf(-gz));
        const float n_ = tanhf(fmaf(r_, sbhh[2 * GSD + k], gn));
        const float hn = (1.f - z_) * n_;
        sx[node][k] = hn;
        h[(size_t)(jb + node) * GSD + k] = hn;
    }
    __syncthreads();

    // ---- phase 1': ai (next step, transposed) / aj from h_new ----
    if (t < 2 * NPB * GMD) {   // 128 threads
        const int which = t >> 6;
        const int node  = (t >> 4) & 3;
        const int m     = t & 15;
        if (which == 0) {
            float a = fmaf(sb[node], swbi[m], sbm[m]);
#pragma unroll
            for (int k = 0; k < GSD; ++k) a = fmaf(sWhi[m][k], sx[node][k], a);
            aiT_out[(size_t)m * GN + jb + node] = a;
        } else {
            float a = sb[node] * swbj[m];
#pragma unroll
            for (int k = 0; k < GSD; ++k) a = fmaf(sWhj[m][k], sx[node][k], a);
            aj[(size_t)(jb + node) * GMD + m] = a;
        }
    }
}

// ---------------- readout + softmax ----------------
__global__ __launch_bounds__(1024)
void final_kernel(const float* __restrict__ h, const float* __restrict__ Wro,
                  const float* __restrict__ bro, float* __restrict__ out)
{
    __shared__ float slog[GN];
    __shared__ float sred[1024];
    __shared__ float swro[GSD];
    const int t = threadIdx.x;
    if (t < GSD) swro[t] = Wro[t];
    __syncthreads();
#pragma unroll
    for (int rr = 0; rr < 2; ++rr) {
        const int i = t + rr * 1024;
        float a = bro[0];
#pragma unroll
        for (int k = 0; k < GSD; ++k) a = fmaf(h[(size_t)i * GSD + k], swro[k], a);
        slog[i] = a;
    }
    __syncthreads();
    sred[t] = fmaxf(slog[t], slog[t + 1024]);
    __syncthreads();
    for (int s = 512; s > 0; s >>= 1) {
        if (t < s) sred[t] = fmaxf(sred[t], sred[t + s]);
        __syncthreads();
    }
    const float gmax = sred[0];
    __syncthreads();
    const float e0 = expf(slog[t] - gmax);
    const float e1 = expf(slog[t + 1024] - gmax);
    sred[t] = e0 + e1;
    __syncthreads();
    for (int s = 512; s > 0; s >>= 1) {
        if (t < s) sred[t] += sred[t + s];
        __syncthreads();
    }
    const float inv = 1.f / sred[0];
    out[t] = e0 * inv;
    out[t + 1024] = e1 * inv;
}

extern "C" void kernel_launch(void* const* d_in, const int* in_sizes, int n_in,
                              void* d_out, int out_size, void* d_ws, size_t ws_size,
                              hipStream_t stream)
{
    const float* J    = (const float*)d_in[0];
    const float* b    = (const float*)d_in[1];
    const float* Wmsg = (const float*)d_in[2];
    const float* bmsg = (const float*)d_in[3];
    const float* Wih  = (const float*)d_in[4];
    // d_in[5] = W_hh: unused by the reference math (only b_hh enters the gates)
    const float* bih  = (const float*)d_in[6];
    const float* bhh  = (const float*)d_in[7];
    const float* Wro  = (const float*)d_in[8];
    const float* bro  = (const float*)d_in[9];
    float* out = (float*)d_out;

    // workspace layout (floats); total ~17.6 MB
    float* ws    = (float*)d_ws;
    float* Jt    = ws;                            // N*N
    float* aiT0  = Jt   + (size_t)GN * GN;        // MD*N (transposed)
    float* aiT1  = aiT0 + (size_t)GN * GMD;       // MD*N (double buffer)
    float* ajb   = aiT1 + (size_t)GN * GMD;       // N*MD
    float* hbuf  = ajb  + (size_t)GN * GMD;       // N*SD
    float* msgb  = hbuf + (size_t)GN * GSD;       // N*MD

    transpose_kernel<<<dim3(32, 32), 256, 0, stream>>>(J, Jt);
    init_kernel<<<GN * GSD / 256, 256, 0, stream>>>(b, Wmsg, bmsg, aiT0, ajb, hbuf, msgb);

    float* ain = aiT0;
    float* aout = aiT1;
    for (int s = 0; s < GSTEPS; ++s) {
        step_kernel<<<NBLK, BLK, 0, stream>>>(Jt, ain, aout, ajb, hbuf, msgb,
                                              b, Wmsg, bmsg, Wih, bih, bhh);
        float* tmp = ain; ain = aout; aout = tmp;
    }
    final_kernel<<<1, 1024, 0, stream>>>(hbuf, Wro, bro, out);
}